// Round 4
// baseline (2116.187 us; speedup 1.0000x reference)
//
#include <hip/hip_runtime.h>

// ---------------------------------------------------------------------------
// TokenRoutedBlock: B=2,T=2048,D=2048,H=16,HD=128,K=4,FF=2048, layer-routed
// mixed linears (4-basis) + causal attention + silu-FFN, bf16 MFMA compute.
// R4: four N=2048 mixed linears as per-basis wide GEMM Z = x*Bcat^T + fused
// alpha-combine epilogues; QKV stays expand-form.
// R6: both GEMMs moved from the m97 2-barrier structure (~770 TF ceiling,
// MfmaUtil 34%, 1.5e8 bank conflicts) to a 256^2-tile deep-pipelined schedule:
// 3-slot LDS ring (BK=32 slices), counted vmcnt(8) (never drained to 0 in the
// main loop), raw s_barrier, T2 XOR-swizzle (pre-swizzled global source +
// swizzled ds_read; LDS dest stays linear for global_load_lds), setprio(1)
// around the MFMA cluster. 8 waves (512 thr), per-wave 128x64 C, 96 KB LDS.
// ---------------------------------------------------------------------------

typedef __attribute__((ext_vector_type(8))) short short8;   // 8 bf16
typedef __attribute__((ext_vector_type(4))) float f32x4;
typedef __attribute__((ext_vector_type(4))) unsigned uint4_t;

#define BT 4096
#define DD 2048
#define KD 8192          // K*D contraction for the qkv expand-form GEMM
#define NH 16
#define HD_ 128
#define RSCALE 0.02209708691207961f      // 1/sqrt(2048)
#define ASCALE 0.08838834764831845f      // 1/sqrt(128)

__device__ inline float bf2f(short s) {
  return __uint_as_float(((unsigned)(unsigned short)s) << 16);
}
__device__ inline short f2bf(float f) {   // RNE
  unsigned u = __float_as_uint(f);
  u += 0x7FFFu + ((u >> 16) & 1u);
  return (short)(u >> 16);
}
__device__ inline f32x4 zero4() { f32x4 v; v[0]=0.f; v[1]=0.f; v[2]=0.f; v[3]=0.f; return v; }

// async 16B global -> LDS (DMA, no VGPR round-trip). LDS dest must be
// wave-uniform base + lane*16 (linear layout, no padding).
__device__ inline void async_copy16(const void* g, void* l) {
  __builtin_amdgcn_global_load_lds(
      (const __attribute__((address_space(1))) unsigned*)g,
      (__attribute__((address_space(3))) unsigned*)l, 16, 0, 0);
}

// ---------------------------------------------------------------------------
// fp32 -> bf16 (truncate) bulk conversion, 8 elems/thread.
__global__ __launch_bounds__(256)
void cvt_bf16_kernel(const float* __restrict__ in, short* __restrict__ out,
                     const int nchunk) {
  const int i = blockIdx.x * 256 + threadIdx.x;
  if (i >= nchunk) return;
  const float* p = in + (size_t)i * 8;
  float4 u0 = *(const float4*)p;
  float4 u1 = *(const float4*)(p + 4);
  uint4_t pk;
  pk[0] = __builtin_amdgcn_perm(__float_as_uint(u0.y), __float_as_uint(u0.x), 0x07060302);
  pk[1] = __builtin_amdgcn_perm(__float_as_uint(u0.w), __float_as_uint(u0.z), 0x07060302);
  pk[2] = __builtin_amdgcn_perm(__float_as_uint(u1.y), __float_as_uint(u1.x), 0x07060302);
  pk[3] = __builtin_amdgcn_perm(__float_as_uint(u1.w), __float_as_uint(u1.z), 0x07060302);
  *(uint4_t*)(out + (size_t)i * 8) = pk;
}

// ---------------------------------------------------------------------------
// RMSNorm * norm_w * gamma + beta  (fp32 in -> bf16 out). One block per token.
__global__ __launch_bounds__(256)
void rmsnorm_kernel(const float* __restrict__ x, const float* __restrict__ w,
                    const float* __restrict__ gamma, const float* __restrict__ beta,
                    short* __restrict__ out) {
  const int t = blockIdx.x;
  const float* xr = x + (size_t)t * DD;
  const int base = threadIdx.x * 8;
  float4 v0 = *(const float4*)(xr + base);
  float4 v1 = *(const float4*)(xr + base + 4);
  float ss = v0.x*v0.x + v0.y*v0.y + v0.z*v0.z + v0.w*v0.w
           + v1.x*v1.x + v1.y*v1.y + v1.z*v1.z + v1.w*v1.w;
  #pragma unroll
  for (int off = 32; off > 0; off >>= 1) ss += __shfl_xor(ss, off, 64);
  __shared__ float red[4];
  const int lane = threadIdx.x & 63, wv = threadIdx.x >> 6;
  if (lane == 0) red[wv] = ss;
  __syncthreads();
  const float tot = red[0] + red[1] + red[2] + red[3];
  const float inv = rsqrtf(tot * (1.0f / DD) + 1.1920929e-07f);
  float xv[8] = {v0.x,v0.y,v0.z,v0.w,v1.x,v1.y,v1.z,v1.w};
  short8 o;
  #pragma unroll
  for (int j = 0; j < 8; ++j)
    o[j] = f2bf(xv[j] * inv * w[base+j] * gamma[base+j] + beta[base+j]);
  *(short8*)(out + (size_t)t * DD + base) = o;
}

// ---------------------------------------------------------------------------
// Routing: logits = (x . route_l)/sqrt(2048) + bias_l ; alpha = softmax_k.
// One wave per token.
__global__ __launch_bounds__(64)
void route_kernel(const short* __restrict__ in,      // (BT, 2048) bf16
                  const float* __restrict__ routeB,  // (L, 4, 2048)
                  const float* __restrict__ biasB,   // (L, 4)
                  const int* __restrict__ li_ptr,
                  float* __restrict__ alpha,         // (BT, 4)
                  float* __restrict__ aout)          // optional copy (a_qkv)
{
  const int t = blockIdx.x;
  const int lane = threadIdx.x;
  const int li = *li_ptr;
  const float* R = routeB + (size_t)li * 4 * DD;
  const float* bias = biasB + li * 4;
  const short* xr = in + (size_t)t * DD;
  float acc0 = 0.f, acc1 = 0.f, acc2 = 0.f, acc3 = 0.f;
  for (int i = lane; i < DD; i += 64) {
    float v = bf2f(xr[i]);
    acc0 += v * R[i];
    acc1 += v * R[DD + i];
    acc2 += v * R[2*DD + i];
    acc3 += v * R[3*DD + i];
  }
  #pragma unroll
  for (int off = 32; off > 0; off >>= 1) {
    acc0 += __shfl_xor(acc0, off, 64);
    acc1 += __shfl_xor(acc1, off, 64);
    acc2 += __shfl_xor(acc2, off, 64);
    acc3 += __shfl_xor(acc3, off, 64);
  }
  if (lane == 0) {
    float lg[4] = {acc0 * RSCALE + bias[0], acc1 * RSCALE + bias[1],
                   acc2 * RSCALE + bias[2], acc3 * RSCALE + bias[3]};
    float mx = fmaxf(fmaxf(lg[0], lg[1]), fmaxf(lg[2], lg[3]));
    float se = 0.f;
    #pragma unroll
    for (int k = 0; k < 4; ++k) { lg[k] = __expf(lg[k] - mx); se += lg[k]; }
    const float rinv = 1.0f / se;
    #pragma unroll
    for (int k = 0; k < 4; ++k) {
      float a = lg[k] * rinv;
      alpha[(size_t)t*4 + k] = a;
      if (aout) aout[(size_t)t*4 + k] = a;
    }
  }
}

// ---------------------------------------------------------------------------
// Expand: Aexp[t, k*2048+d] = alpha[t,k] * in[t,d]   (bf16) — qkv path only.
__global__ __launch_bounds__(256)
void expand_kernel(const short* __restrict__ in, const float* __restrict__ alpha,
                   short* __restrict__ out)   // (BT, 8192)
{
  const int t = blockIdx.x;
  const short* hr = in + (size_t)t * DD;
  const float a0 = alpha[(size_t)t*4], a1 = alpha[(size_t)t*4+1],
              a2 = alpha[(size_t)t*4+2], a3 = alpha[(size_t)t*4+3];
  const float av[4] = {a0, a1, a2, a3};
  #pragma unroll
  for (int c = 0; c < 4; ++c) {
    int ci = threadIdx.x + 256 * c;       // chunk of 8 elems, 1024 chunks
    int kk = ci * 8;
    int kidx = kk >> 11;
    int d = kk & 2047;
    short8 v = *(const short8*)(hr + d);
    float s = av[kidx];
    short8 o;
    #pragma unroll
    for (int j = 0; j < 8; ++j) o[j] = f2bf(bf2f(v[j]) * s);
    *(short8*)(out + (size_t)t * KD + kk) = o;
  }
}

// ---------------------------------------------------------------------------
// Deep-pipelined 256x256-tile GEMM (8 waves, per-wave 128x64 C).
//   C(4096 x NST) bf16 = A(4096 x AST) * B^T
// QKV=true : A = Aexp (AST=8192, K=8192), B = (4,6144,2048) basis-indexed.
// QKV=false: A (AST=2048, K=2048), B = Bc (NST x 2048) plain.
// Schedule: 3-slot LDS ring of BK=32 K-slices (A:16KB + B:16KB per slot).
// Per phase: vmcnt(8) [slice's 4 loads landed, 8 newer stay in flight] ->
// s_barrier -> 12x ds_read_b128 -> lgkmcnt(0)+sched_barrier -> setprio(1) ->
// 32 MFMA -> setprio(0) -> s_barrier -> stage slice+3 (4x global_load_lds).
// T2 swizzle: LDS linear (DMA dest); global SOURCE col-granule pre-permuted
// cg ^= (row>>1)&3; ds_read uses the same XOR -> 16 lr-rows spread across all
// 8 16B bank slots (2-way = free) instead of 8-way conflict.
__global__ __launch_bounds__(512)
void gemm8p_qkv(const short* __restrict__ A, const short* __restrict__ B,
                short* __restrict__ C);

template<bool QKV, int AST, int KTOT, int NST>
__global__ __launch_bounds__(512)
void gemm8p(const short* __restrict__ A, const short* __restrict__ B,
            short* __restrict__ C)
{
  constexpr int NS = KTOT / 32;          // K-slices
  __shared__ __align__(16) short As[3][256 * 32];   // 3 x 16 KB
  __shared__ __align__(16) short Bs[3][256 * 32];   // 3 x 16 KB
  const int tid = threadIdx.x;
  const int lane = tid & 63, wave = tid >> 6;
  const int lr = lane & 15, lg = lane >> 4;
  const int wm = wave >> 2, wn = wave & 3;          // 2(M) x 4(N) waves
  const int m0 = blockIdx.y * 256, n0 = blockIdx.x * 256;

  // staging: thread covers 16B granules tid (rows 0-127) and 512+tid (128-255)
  const int srow = tid >> 2;                        // 0..127
  const int pc = (tid & 3) ^ ((tid >> 3) & 3);      // swizzled source col-granule
  const short* Aab = A + (size_t)(m0 + srow) * AST + pc * 8;
  const short* Bab = B + (size_t)(n0 + srow) * 2048 + pc * 8;

  f32x4 acc[8][4];
  #pragma unroll
  for (int i = 0; i < 8; ++i)
    #pragma unroll
    for (int j = 0; j < 4; ++j) acc[i][j] = zero4();

  auto stage = [&](int ks_) {
    const int b_ = ks_ % 3;
    short* la = &As[b_][0] + tid * 8;
    short* lb = &Bs[b_][0] + tid * 8;
    if constexpr (QKV) {
      const int kidx = ks_ >> 6;                    // which basis
      const int dbase = (ks_ & 63) * 32;            // offset within D
      const short* as_ = Aab + ks_ * 32;
      const short* bs_ = Bab + (size_t)kidx * (6144 * 2048) + dbase;
      async_copy16(as_, la);
      async_copy16(as_ + 128 * AST, la + 4096);
      async_copy16(bs_, lb);
      async_copy16(bs_ + 128 * 2048, lb + 4096);
    } else {
      const int k0 = ks_ * 32;
      async_copy16(Aab + k0, la);
      async_copy16(Aab + k0 + 128 * AST, la + 4096);
      async_copy16(Bab + k0, lb);
      async_copy16(Bab + k0 + 128 * 2048, lb + 4096);
    }
  };

  stage(0); stage(1); stage(2);                     // prologue: 12 loads in flight

  const int acol = (lg ^ ((lr >> 1) & 3)) * 8;      // swizzled read col (shorts)

  for (int ks = 0; ks < NS; ++ks) {
    const int b = ks % 3;
    const int rem = NS - 1 - ks;
    if (rem >= 2)      asm volatile("s_waitcnt vmcnt(8)" ::: "memory");
    else if (rem == 1) asm volatile("s_waitcnt vmcnt(4)" ::: "memory");
    else               asm volatile("s_waitcnt vmcnt(0)" ::: "memory");
    __builtin_amdgcn_s_barrier();                   // slice ks present for all
    short8 af[8], bg[4];
    const short* ap = &As[b][0] + (wm * 128 + lr) * 32 + acol;
    #pragma unroll
    for (int i = 0; i < 8; ++i) af[i] = *(const short8*)(ap + i * 512);
    const short* bp = &Bs[b][0] + (wn * 64 + lr) * 32 + acol;
    #pragma unroll
    for (int j = 0; j < 4; ++j) bg[j] = *(const short8*)(bp + j * 512);
    asm volatile("s_waitcnt lgkmcnt(0)" ::: "memory");
    __builtin_amdgcn_sched_barrier(0);
    __builtin_amdgcn_s_setprio(1);
    #pragma unroll
    for (int i = 0; i < 8; ++i)
      #pragma unroll
      for (int j = 0; j < 4; ++j)
        acc[i][j] = __builtin_amdgcn_mfma_f32_16x16x32_bf16(af[i], bg[j], acc[i][j], 0, 0, 0);
    __builtin_amdgcn_s_setprio(0);
    __builtin_amdgcn_s_barrier();                   // all reads of slot b done
    if (ks + 3 < NS) stage(ks + 3);                 // safe: slot b fully consumed
  }

  // epilogue; C layout: col = lane&15, row = (lane>>4)*4 + reg
  #pragma unroll
  for (int i = 0; i < 8; ++i)
    #pragma unroll
    for (int r = 0; r < 4; ++r) {
      const int m = m0 + wm * 128 + i * 16 + lg * 4 + r;
      #pragma unroll
      for (int j = 0; j < 4; ++j) {
        const int n = n0 + wn * 64 + j * 16 + lr;
        C[(size_t)m * NST + n] = f2bf(acc[i][j][r]);
      }
    }
}

// ---------------------------------------------------------------------------
// Alpha-combine + fused epilogues. y[t,d] = sum_k alpha[t,k]*Z[t,k*2048+d].
// mode 0: bf16 out = y                      (gate)
// mode 1: fp32 out = x + y                  (o residual -> x_attn)
// mode 2: bf16 out = silu(gate)*y           (up; gate read bf16, in-place ok)
// mode 3: fp32 out = x + (xattn + y - x)*is (down final)
// One block per token; thread handles 8 consecutive d.
__global__ __launch_bounds__(256)
void combine_kernel(const short* __restrict__ Z,      // (4096, 8192) bf16
                    const float* __restrict__ alpha,  // (4096, 4)
                    const int mode,
                    const float* __restrict__ x,
                    const float* __restrict__ xattn,
                    const float* __restrict__ iter_s,
                    const short* __restrict__ gate,
                    void* __restrict__ outp)
{
  const int t = blockIdx.x;
  const int d0 = threadIdx.x * 8;
  const float a0 = alpha[(size_t)t*4],   a1 = alpha[(size_t)t*4+1],
              a2 = alpha[(size_t)t*4+2], a3 = alpha[(size_t)t*4+3];
  const short* zr = Z + (size_t)t * 8192 + d0;
  short8 z0 = *(const short8*)(zr);
  short8 z1 = *(const short8*)(zr + 2048);
  short8 z2 = *(const short8*)(zr + 4096);
  short8 z3 = *(const short8*)(zr + 6144);
  float y[8];
  #pragma unroll
  for (int j = 0; j < 8; ++j)
    y[j] = a0*bf2f(z0[j]) + a1*bf2f(z1[j]) + a2*bf2f(z2[j]) + a3*bf2f(z3[j]);
  const size_t base = (size_t)t * DD + d0;
  if (mode == 0) {
    short8 o;
    #pragma unroll
    for (int j = 0; j < 8; ++j) o[j] = f2bf(y[j]);
    *(short8*)((short*)outp + base) = o;
  } else if (mode == 1) {
    float4 x0 = *(const float4*)(x + base);
    float4 x1 = *(const float4*)(x + base + 4);
    float xv[8] = {x0.x,x0.y,x0.z,x0.w,x1.x,x1.y,x1.z,x1.w};
    float* op = (float*)outp;
    #pragma unroll
    for (int j = 0; j < 8; ++j) op[base + j] = xv[j] + y[j];
  } else if (mode == 2) {
    short8 gv = *(const short8*)(gate + base);
    short8 o;
    #pragma unroll
    for (int j = 0; j < 8; ++j) {
      float xg = bf2f(gv[j]);
      float s = xg / (1.0f + __expf(-xg));
      o[j] = f2bf(s * y[j]);
    }
    *(short8*)((short*)outp + base) = o;
  } else {
    const float is = *iter_s;
    float4 x0 = *(const float4*)(x + base);
    float4 x1 = *(const float4*)(x + base + 4);
    float4 t0 = *(const float4*)(xattn + base);
    float4 t1 = *(const float4*)(xattn + base + 4);
    float xv[8] = {x0.x,x0.y,x0.z,x0.w,x1.x,x1.y,x1.z,x1.w};
    float tv[8] = {t0.x,t0.y,t0.z,t0.w,t1.x,t1.y,t1.z,t1.w};
    float* op = (float*)outp;
    #pragma unroll
    for (int j = 0; j < 8; ++j) op[base + j] = xv[j] + (tv[j] + y[j] - xv[j]) * is;
  }
}

// ---------------------------------------------------------------------------
// Transpose V out of qkv into (B*H, HD, T) bf16 so attention can stage V^T
// with vector loads.
__global__ __launch_bounds__(256)
void transpose_v_kernel(const short* __restrict__ qkv, short* __restrict__ vt)
{
  __shared__ __align__(16) short tile[64][72];
  const int t0 = blockIdx.x * 64;
  const int hd0 = blockIdx.y * 64;
  const int bh = blockIdx.z;
  const int b = bh >> 4, h = bh & 15;
  const int tid = threadIdx.x;
  #pragma unroll
  for (int c = 0; c < 2; ++c) {
    int ci = tid + 256 * c;
    int tr = ci >> 3, c8 = ci & 7;
    *(short8*)&tile[tr][c8*8] =
      *(const short8*)(qkv + (size_t)(b*2048 + t0 + tr)*6144 + 4096 + h*HD_ + hd0 + c8*8);
  }
  __syncthreads();
  #pragma unroll
  for (int c = 0; c < 2; ++c) {
    int ci = tid + 256 * c;
    int hr = ci >> 3, c8 = ci & 7;
    short8 o;
    #pragma unroll
    for (int j = 0; j < 8; ++j) o[j] = tile[c8*8 + j][hr];
    *(short8*)(vt + (size_t)(bh*HD_ + hd0 + hr)*2048 + t0 + c8*8) = o;
  }
}

// ---------------------------------------------------------------------------
// Flash attention (causal). Block = 4 waves; wave w owns 16 q-rows.
// Tiles of 32 keys; QK^T and PV via 16x16x32 bf16 MFMA; P goes through LDS
// (C-layout -> A-layout).
__global__ __launch_bounds__(256, 2)
void attn_kernel(const short* __restrict__ qkv,   // (4096, 6144) bf16
                 const short* __restrict__ vt,    // (32, 128, 2048) bf16
                 short* __restrict__ attnout)     // (4096, 2048) bf16
{
  __shared__ __align__(16) short Ks[32][136];
  __shared__ __align__(16) short Vt[128][40];
  __shared__ __align__(16) short Ps[4][16][40];
  const int bid = blockIdx.x;
  const int qt = bid & 31, bh = bid >> 5;
  const int b = bh >> 4, h = bh & 15;
  const int q0 = qt * 64;
  const int tid = threadIdx.x, lane = tid & 63, w = tid >> 6;
  const int lr = lane & 15, lg = lane >> 4;
  const int q0w = q0 + w * 16;

  // preload Q fragments: A[m=lr][k = s*32 + lg*8 + j]
  short8 qf[4];
  {
    const size_t qbase = (size_t)(b*2048 + q0w + lr) * 6144 + h * HD_;
    #pragma unroll
    for (int s = 0; s < 4; ++s)
      qf[s] = *(const short8*)(qkv + qbase + s*32 + lg*8);
  }
  float m_run[4], l_run[4];
  f32x4 acc[8];
  #pragma unroll
  for (int r = 0; r < 4; ++r) { m_run[r] = -1e30f; l_run[r] = 0.f; }
  #pragma unroll
  for (int dt = 0; dt < 8; ++dt) acc[dt] = zero4();

  const int ntiles = (q0 + 64) >> 5;
  for (int jt = 0; jt < ntiles; ++jt) {
    const int j0 = jt << 5;
    // stage K tile (32 x 128) and V^T tile (128 x 32)
    #pragma unroll
    for (int c = 0; c < 2; ++c) {
      int ci = tid + 256 * c;
      int key = ci >> 4, hd8 = ci & 15;
      *(short8*)&Ks[key][hd8*8] =
        *(const short8*)(qkv + (size_t)(b*2048 + j0 + key)*6144 + 2048 + h*HD_ + hd8*8);
    }
    #pragma unroll
    for (int c = 0; c < 2; ++c) {
      int ci = tid + 256 * c;
      int hd = ci >> 2, k8 = ci & 3;
      *(short8*)&Vt[hd][k8*8] =
        *(const short8*)(vt + (size_t)(bh*HD_ + hd)*2048 + j0 + k8*8);
    }
    __syncthreads();
    // S = Q K^T  (two 16-key halves)
    f32x4 sc0 = zero4(), sc1 = zero4();
    #pragma unroll
    for (int s = 0; s < 4; ++s) {
      short8 kb0 = *(const short8*)&Ks[lr][s*32 + lg*8];
      short8 kb1 = *(const short8*)&Ks[16 + lr][s*32 + lg*8];
      sc0 = __builtin_amdgcn_mfma_f32_16x16x32_bf16(qf[s], kb0, sc0, 0, 0, 0);
      sc1 = __builtin_amdgcn_mfma_f32_16x16x32_bf16(qf[s], kb1, sc1, 0, 0, 0);
    }
    // online softmax (per row r; columns spread over lr lanes)
    float pv0[4], pv1[4], al[4];
    #pragma unroll
    for (int r = 0; r < 4; ++r) {
      const int q = q0w + lg*4 + r;
      float v0 = sc0[r] * ASCALE; if (j0 + lr > q)      v0 = -1e30f;
      float v1 = sc1[r] * ASCALE; if (j0 + 16 + lr > q) v1 = -1e30f;
      float mx = fmaxf(v0, v1);
      mx = fmaxf(mx, __shfl_xor(mx, 1, 16));
      mx = fmaxf(mx, __shfl_xor(mx, 2, 16));
      mx = fmaxf(mx, __shfl_xor(mx, 4, 16));
      mx = fmaxf(mx, __shfl_xor(mx, 8, 16));
      const float mnew = fmaxf(m_run[r], mx);
      const float a = __expf(m_run[r] - mnew);
      v0 = __expf(v0 - mnew);
      v1 = __expf(v1 - mnew);
      float rs = v0 + v1;
      rs += __shfl_xor(rs, 1, 16);
      rs += __shfl_xor(rs, 2, 16);
      rs += __shfl_xor(rs, 4, 16);
      rs += __shfl_xor(rs, 8, 16);
      l_run[r] = l_run[r] * a + rs;
      m_run[r] = mnew;
      al[r] = a; pv0[r] = v0; pv1[r] = v1;
    }
    #pragma unroll
    for (int dt = 0; dt < 8; ++dt)
      #pragma unroll
      for (int r = 0; r < 4; ++r) acc[dt][r] *= al[r];
    // P: C-layout -> LDS -> A-layout
    #pragma unroll
    for (int r = 0; r < 4; ++r) {
      Ps[w][lg*4 + r][lr]      = f2bf(pv0[r]);
      Ps[w][lg*4 + r][16 + lr] = f2bf(pv1[r]);
    }
    short8 pa = *(const short8*)&Ps[w][lr][lg*8];
    #pragma unroll
    for (int dt = 0; dt < 8; ++dt) {
      short8 vb = *(const short8*)&Vt[dt*16 + lr][lg*8];
      acc[dt] = __builtin_amdgcn_mfma_f32_16x16x32_bf16(pa, vb, acc[dt], 0, 0, 0);
    }
    __syncthreads();
  }
  #pragma unroll
  for (int dt = 0; dt < 8; ++dt) {
    #pragma unroll
    for (int r = 0; r < 4; ++r) {
      const int q = q0w + lg*4 + r;
      attnout[(size_t)(b*2048 + q)*2048 + h*HD_ + dt*16 + lr] = f2bf(acc[dt][r] / l_run[r]);
    }
  }
}

// ---------------------------------------------------------------------------
extern "C" void kernel_launch(void* const* d_in, const int* in_sizes, int n_in,
                              void* d_out, int out_size, void* d_ws, size_t ws_size,
                              hipStream_t stream) {
  const float* x          = (const float*)d_in[0];
  const float* gamma      = (const float*)d_in[1];
  const float* beta       = (const float*)d_in[2];
  const float* iter_scale = (const float*)d_in[3];
  const float* qkv_bases  = (const float*)d_in[4];
  const float* o_bases    = (const float*)d_in[5];
  const float* gate_bases = (const float*)d_in[6];
  const float* up_bases   = (const float*)d_in[7];
  const float* down_bases = (const float*)d_in[8];
  const float* route_qkv  = (const float*)d_in[9];
  const float* route_o    = (const float*)d_in[10];
  const float* route_gate = (const float*)d_in[11];
  const float* route_up   = (const float*)d_in[12];
  const float* route_down = (const float*)d_in[13];
  const float* bias_qkv   = (const float*)d_in[14];
  const float* bias_o     = (const float*)d_in[15];
  const float* bias_gate  = (const float*)d_in[16];
  const float* bias_up    = (const float*)d_in[17];
  const float* bias_down  = (const float*)d_in[18];
  const float* norm1_w    = (const float*)d_in[19];
  const float* norm2_w    = (const float*)d_in[20];
  const int*   li         = (const int*)d_in[21];

  float* out0 = (float*)d_out;                  // (B,T,D) fp32
  float* aout = out0 + (size_t)BT * DD;         // a_qkv (B,T,4) fp32

  char* ws = (char*)d_ws;
  short* hbuf    = (short*)(ws + 0);            // 16.78 MB  (h / h2, bf16)
  float* alpha   = (float*)(ws + 16777216);     // 64 KB
  short* Zbuf    = (short*)(ws + 16842752);     // 67.1 MB  (Z wide / Aexp qkv)
  short* Bconv   = (short*)(ws + 83951616);     // 100.7 MB (bf16 bases, reused)
  short* qkvbuf  = (short*)(ws + 184614912);    // 50.3 MB  (BT x 6144 bf16)
  short* vtbuf   = (short*)(ws + 234946560);    // 16.78 MB
  short* attnout = (short*)(ws + 251723776);    // 16.78 MB ; total 268.5 MB
  // aliases (lifetimes are disjoint): after attn, qkvbuf region splits into
  // x_attn (fp32, 33.55 MB) + gate/ffn (bf16, 16.78 MB).
  float* x_attn  = (float*)(ws + 184614912);
  short* gatebuf = (short*)(ws + 218169344);    // also ffn_in (in-place mode 2)

  const int NCH_QKV = 50331648 / 8;   // qkv_bases chunks
  const int NCH_D   = 16777216 / 8;   // o/gate/up/down bases chunks

  // h = rmsnorm(x, norm1_w)*gamma + beta
  rmsnorm_kernel<<<BT, 256, 0, stream>>>(x, norm1_w, gamma, beta, hbuf);
  // qkv mixed linear (expand form, emits a_qkv)
  cvt_bf16_kernel<<<NCH_QKV/256, 256, 0, stream>>>(qkv_bases, Bconv, NCH_QKV);
  route_kernel<<<BT, 64, 0, stream>>>(hbuf, route_qkv, bias_qkv, li, alpha, aout);
  expand_kernel<<<BT, 256, 0, stream>>>(hbuf, alpha, Zbuf);
  gemm8p<true, 8192, 8192, 6144><<<dim3(24, 16), 512, 0, stream>>>(Zbuf, Bconv, qkvbuf);
  // attention
  transpose_v_kernel<<<dim3(32, 2, 32), 256, 0, stream>>>(qkvbuf, vtbuf);
  attn_kernel<<<1024, 256, 0, stream>>>(qkvbuf, vtbuf, attnout);
  // o mixed linear (wide form) + residual -> x_attn (fp32)
  cvt_bf16_kernel<<<NCH_D/256, 256, 0, stream>>>(o_bases, Bconv, NCH_D);
  route_kernel<<<BT, 64, 0, stream>>>(attnout, route_o, bias_o, li, alpha, nullptr);
  gemm8p<false, 2048, 2048, 8192><<<dim3(32, 16), 512, 0, stream>>>(attnout, Bconv, Zbuf);
  combine_kernel<<<BT, 256, 0, stream>>>(Zbuf, alpha, 1, x, nullptr, nullptr,
                                         nullptr, x_attn);
  // h2 = rmsnorm(x_attn, norm2_w)*gamma + beta
  rmsnorm_kernel<<<BT, 256, 0, stream>>>(x_attn, norm2_w, gamma, beta, hbuf);
  // gate (wide form)
  cvt_bf16_kernel<<<NCH_D/256, 256, 0, stream>>>(gate_bases, Bconv, NCH_D);
  route_kernel<<<BT, 64, 0, stream>>>(hbuf, route_gate, bias_gate, li, alpha, nullptr);
  gemm8p<false, 2048, 2048, 8192><<<dim3(32, 16), 512, 0, stream>>>(hbuf, Bconv, Zbuf);
  combine_kernel<<<BT, 256, 0, stream>>>(Zbuf, alpha, 0, nullptr, nullptr, nullptr,
                                         nullptr, gatebuf);
  // up (wide form) + fused silu(gate)*up -> ffn_in (in-place over gatebuf)
  cvt_bf16_kernel<<<NCH_D/256, 256, 0, stream>>>(up_bases, Bconv, NCH_D);
  route_kernel<<<BT, 64, 0, stream>>>(hbuf, route_up, bias_up, li, alpha, nullptr);
  gemm8p<false, 2048, 2048, 8192><<<dim3(32, 16), 512, 0, stream>>>(hbuf, Bconv, Zbuf);
  combine_kernel<<<BT, 256, 0, stream>>>(Zbuf, alpha, 2, nullptr, nullptr, nullptr,
                                         gatebuf, gatebuf);
  // down (wide form) + final residual/iter_scale -> out0
  cvt_bf16_kernel<<<NCH_D/256, 256, 0, stream>>>(down_bases, Bconv, NCH_D);
  route_kernel<<<BT, 64, 0, stream>>>(gatebuf, route_down, bias_down, li, alpha, nullptr);
  gemm8p<false, 2048, 2048, 8192><<<dim3(32, 16), 512, 0, stream>>>(gatebuf, Bconv, Zbuf);
  combine_kernel<<<BT, 256, 0, stream>>>(Zbuf, alpha, 3, x, x_attn, iter_scale,
                                         nullptr, out0);
}

// Round 5
// 1931.625 us; speedup vs baseline: 1.0955x; 1.0955x over previous
//
#include <hip/hip_runtime.h>

// ---------------------------------------------------------------------------
// TokenRoutedBlock: B=2,T=2048,D=2048,H=16,HD=128,K=4,FF=2048, layer-routed
// mixed linears (4-basis) + causal attention + silu-FFN, bf16 MFMA compute.
// R4: four N=2048 mixed linears as per-basis wide GEMM Z = x*Bcat^T + fused
// alpha-combine epilogues; QKV stays expand-form.
// R6: deep-pipeline attempt at BK=32 (3-slot ring): swizzle verified (bank
// conflicts 1.5e8 -> 0) but phase too small: 64 MFMA/SIMD (~1240cy) vs
// ~2000cy fixed phase overhead -> util 28%, regressed.
// R7: BK=64, 2-slot double buffer (128 KB LDS), stage issued BEFORE the
// counted vmcnt(8) wait so loads fly a full ~2500cy phase. 128 MFMA/SIMD per
// phase amortizes the barrier/latency overhead (m201 geometry: 62% util).
// ---------------------------------------------------------------------------

typedef __attribute__((ext_vector_type(8))) short short8;   // 8 bf16
typedef __attribute__((ext_vector_type(4))) float f32x4;
typedef __attribute__((ext_vector_type(4))) unsigned uint4_t;

#define BT 4096
#define DD 2048
#define KD 8192          // K*D contraction for the qkv expand-form GEMM
#define NH 16
#define HD_ 128
#define RSCALE 0.02209708691207961f      // 1/sqrt(2048)
#define ASCALE 0.08838834764831845f      // 1/sqrt(128)

__device__ inline float bf2f(short s) {
  return __uint_as_float(((unsigned)(unsigned short)s) << 16);
}
__device__ inline short f2bf(float f) {   // RNE
  unsigned u = __float_as_uint(f);
  u += 0x7FFFu + ((u >> 16) & 1u);
  return (short)(u >> 16);
}
__device__ inline f32x4 zero4() { f32x4 v; v[0]=0.f; v[1]=0.f; v[2]=0.f; v[3]=0.f; return v; }

// async 16B global -> LDS (DMA, no VGPR round-trip). LDS dest must be
// wave-uniform base + lane*16 (linear layout, no padding).
__device__ inline void async_copy16(const void* g, void* l) {
  __builtin_amdgcn_global_load_lds(
      (const __attribute__((address_space(1))) unsigned*)g,
      (__attribute__((address_space(3))) unsigned*)l, 16, 0, 0);
}

// ---------------------------------------------------------------------------
// fp32 -> bf16 (truncate) bulk conversion, 8 elems/thread.
__global__ __launch_bounds__(256)
void cvt_bf16_kernel(const float* __restrict__ in, short* __restrict__ out,
                     const int nchunk) {
  const int i = blockIdx.x * 256 + threadIdx.x;
  if (i >= nchunk) return;
  const float* p = in + (size_t)i * 8;
  float4 u0 = *(const float4*)p;
  float4 u1 = *(const float4*)(p + 4);
  uint4_t pk;
  pk[0] = __builtin_amdgcn_perm(__float_as_uint(u0.y), __float_as_uint(u0.x), 0x07060302);
  pk[1] = __builtin_amdgcn_perm(__float_as_uint(u0.w), __float_as_uint(u0.z), 0x07060302);
  pk[2] = __builtin_amdgcn_perm(__float_as_uint(u1.y), __float_as_uint(u1.x), 0x07060302);
  pk[3] = __builtin_amdgcn_perm(__float_as_uint(u1.w), __float_as_uint(u1.z), 0x07060302);
  *(uint4_t*)(out + (size_t)i * 8) = pk;
}

// ---------------------------------------------------------------------------
// RMSNorm * norm_w * gamma + beta  (fp32 in -> bf16 out). One block per token.
__global__ __launch_bounds__(256)
void rmsnorm_kernel(const float* __restrict__ x, const float* __restrict__ w,
                    const float* __restrict__ gamma, const float* __restrict__ beta,
                    short* __restrict__ out) {
  const int t = blockIdx.x;
  const float* xr = x + (size_t)t * DD;
  const int base = threadIdx.x * 8;
  float4 v0 = *(const float4*)(xr + base);
  float4 v1 = *(const float4*)(xr + base + 4);
  float ss = v0.x*v0.x + v0.y*v0.y + v0.z*v0.z + v0.w*v0.w
           + v1.x*v1.x + v1.y*v1.y + v1.z*v1.z + v1.w*v1.w;
  #pragma unroll
  for (int off = 32; off > 0; off >>= 1) ss += __shfl_xor(ss, off, 64);
  __shared__ float red[4];
  const int lane = threadIdx.x & 63, wv = threadIdx.x >> 6;
  if (lane == 0) red[wv] = ss;
  __syncthreads();
  const float tot = red[0] + red[1] + red[2] + red[3];
  const float inv = rsqrtf(tot * (1.0f / DD) + 1.1920929e-07f);
  float xv[8] = {v0.x,v0.y,v0.z,v0.w,v1.x,v1.y,v1.z,v1.w};
  short8 o;
  #pragma unroll
  for (int j = 0; j < 8; ++j)
    o[j] = f2bf(xv[j] * inv * w[base+j] * gamma[base+j] + beta[base+j]);
  *(short8*)(out + (size_t)t * DD + base) = o;
}

// ---------------------------------------------------------------------------
// Routing: logits = (x . route_l)/sqrt(2048) + bias_l ; alpha = softmax_k.
// One wave per token.
__global__ __launch_bounds__(64)
void route_kernel(const short* __restrict__ in,      // (BT, 2048) bf16
                  const float* __restrict__ routeB,  // (L, 4, 2048)
                  const float* __restrict__ biasB,   // (L, 4)
                  const int* __restrict__ li_ptr,
                  float* __restrict__ alpha,         // (BT, 4)
                  float* __restrict__ aout)          // optional copy (a_qkv)
{
  const int t = blockIdx.x;
  const int lane = threadIdx.x;
  const int li = *li_ptr;
  const float* R = routeB + (size_t)li * 4 * DD;
  const float* bias = biasB + li * 4;
  const short* xr = in + (size_t)t * DD;
  float acc0 = 0.f, acc1 = 0.f, acc2 = 0.f, acc3 = 0.f;
  for (int i = lane; i < DD; i += 64) {
    float v = bf2f(xr[i]);
    acc0 += v * R[i];
    acc1 += v * R[DD + i];
    acc2 += v * R[2*DD + i];
    acc3 += v * R[3*DD + i];
  }
  #pragma unroll
  for (int off = 32; off > 0; off >>= 1) {
    acc0 += __shfl_xor(acc0, off, 64);
    acc1 += __shfl_xor(acc1, off, 64);
    acc2 += __shfl_xor(acc2, off, 64);
    acc3 += __shfl_xor(acc3, off, 64);
  }
  if (lane == 0) {
    float lg[4] = {acc0 * RSCALE + bias[0], acc1 * RSCALE + bias[1],
                   acc2 * RSCALE + bias[2], acc3 * RSCALE + bias[3]};
    float mx = fmaxf(fmaxf(lg[0], lg[1]), fmaxf(lg[2], lg[3]));
    float se = 0.f;
    #pragma unroll
    for (int k = 0; k < 4; ++k) { lg[k] = __expf(lg[k] - mx); se += lg[k]; }
    const float rinv = 1.0f / se;
    #pragma unroll
    for (int k = 0; k < 4; ++k) {
      float a = lg[k] * rinv;
      alpha[(size_t)t*4 + k] = a;
      if (aout) aout[(size_t)t*4 + k] = a;
    }
  }
}

// ---------------------------------------------------------------------------
// Expand: Aexp[t, k*2048+d] = alpha[t,k] * in[t,d]   (bf16) — qkv path only.
__global__ __launch_bounds__(256)
void expand_kernel(const short* __restrict__ in, const float* __restrict__ alpha,
                   short* __restrict__ out)   // (BT, 8192)
{
  const int t = blockIdx.x;
  const short* hr = in + (size_t)t * DD;
  const float a0 = alpha[(size_t)t*4], a1 = alpha[(size_t)t*4+1],
              a2 = alpha[(size_t)t*4+2], a3 = alpha[(size_t)t*4+3];
  const float av[4] = {a0, a1, a2, a3};
  #pragma unroll
  for (int c = 0; c < 4; ++c) {
    int ci = threadIdx.x + 256 * c;       // chunk of 8 elems, 1024 chunks
    int kk = ci * 8;
    int kidx = kk >> 11;
    int d = kk & 2047;
    short8 v = *(const short8*)(hr + d);
    float s = av[kidx];
    short8 o;
    #pragma unroll
    for (int j = 0; j < 8; ++j) o[j] = f2bf(bf2f(v[j]) * s);
    *(short8*)(out + (size_t)t * KD + kk) = o;
  }
}

// ---------------------------------------------------------------------------
// Deep-pipelined 256x256-tile GEMM, BK=64, 2-slot LDS double buffer (128 KB).
//   C(4096 x NST) bf16 = A(4096 x AST) * B^T
// QKV=true : A = Aexp (AST=8192, K=8192), B = (4,6144,2048) basis-indexed.
// QKV=false: A (AST=2048, K=2048), B = Bc (NST x 2048) plain.
// 8 waves (512 thr), wave (wm,wn) in 2Mx4N owns 128x64 of C.
// Per phase ks: issue stage(ks+1) into slot ks+1 (8 global_load_lds/thread)
// -> s_waitcnt vmcnt(8) [= exactly those 8; slice ks's loads landed] ->
// s_barrier -> per k-half {12x ds_read_b128 -> lgkmcnt(0)+sched_barrier ->
// setprio(1) -> 32 MFMA -> setprio(0)} x2 -> s_barrier.
// Slot safety: slot (ks+1)&1 was last READ in phase ks-1, sealed by that
// phase's closing barrier which precedes this issue point.
// T2 swizzle (verified 0 conflicts in R6): LDS linear (DMA dest); source col
// granule pre-permuted cg^(row&7); read granule (kh*4+lg)^(lr&7) -> 16
// lr-rows spread over 8 bank slots = 2-way = free.
template<bool QKV, int AST, int KTOT, int NST>
__global__ __launch_bounds__(512)
void gemm_dp(const short* __restrict__ A, const short* __restrict__ B,
             short* __restrict__ C)
{
  constexpr int NS = KTOT / 64;                     // K-slices of 64
  __shared__ __align__(16) short As[2][256 * 64];   // 2 x 32 KB
  __shared__ __align__(16) short Bs[2][256 * 64];   // 2 x 32 KB
  const int tid = threadIdx.x;
  const int lane = tid & 63, wave = tid >> 6;
  const int lr = lane & 15, lg = lane >> 4;
  const int wm = wave >> 2, wn = wave & 3;          // 2(M) x 4(N) waves
  const int m0 = blockIdx.y * 256, n0 = blockIdx.x * 256;

  // staging geometry: granule g = c*512 + tid (c=0..3) covers
  // (row = c*64 + tid>>3, col granule tid&7); source col pre-swizzled.
  const int srow0 = tid >> 3;                       // 0..63
  const int scg = (tid & 7) ^ (srow0 & 7);          // swizzled source granule
  const short* Aab = A + (size_t)(m0 + srow0) * AST + scg * 8;
  const short* Bab = B + (size_t)(n0 + srow0) * 2048 + scg * 8;

  f32x4 acc[8][4];
  #pragma unroll
  for (int i = 0; i < 8; ++i)
    #pragma unroll
    for (int j = 0; j < 4; ++j) acc[i][j] = zero4();

  auto stage = [&](int s, int ks) {
    short* la = &As[s][0] + tid * 8;
    short* lb = &Bs[s][0] + tid * 8;
    const int k0 = ks * 64;
    if constexpr (QKV) {
      const int kidx = ks >> 5;                     // basis (64-slices don't cross 2048)
      const size_t boff = (size_t)kidx * (6144 * 2048) + (ks & 31) * 64;
      #pragma unroll
      for (int c = 0; c < 4; ++c) {
        async_copy16(Aab + (size_t)(c * 64) * AST + k0, la + c * 4096);
        async_copy16(Bab + (size_t)(c * 64) * 2048 + boff, lb + c * 4096);
      }
    } else {
      #pragma unroll
      for (int c = 0; c < 4; ++c) {
        async_copy16(Aab + (size_t)(c * 64) * AST + k0, la + c * 4096);
        async_copy16(Bab + (size_t)(c * 64) * 2048 + k0, lb + c * 4096);
      }
    }
  };

  stage(0, 0);                                      // prologue: 8 loads in flight

  for (int ks = 0; ks < NS; ++ks) {
    const int s = ks & 1;
    if (ks + 1 < NS) {
      stage(s ^ 1, ks + 1);                         // issue next slice early
      asm volatile("s_waitcnt vmcnt(8)" ::: "memory");   // slice ks landed
    } else {
      asm volatile("s_waitcnt vmcnt(0)" ::: "memory");
    }
    __builtin_amdgcn_s_barrier();                   // slice ks visible to all
    #pragma unroll
    for (int kh = 0; kh < 2; ++kh) {
      short8 af[8], bg[4];
      #pragma unroll
      for (int i = 0; i < 8; ++i) {
        const int row = wm * 128 + i * 16 + lr;
        const int rg = (kh * 4 + lg) ^ (row & 7);
        af[i] = *(const short8*)(&As[s][0] + row * 64 + rg * 8);
      }
      #pragma unroll
      for (int j = 0; j < 4; ++j) {
        const int row = wn * 64 + j * 16 + lr;
        const int rg = (kh * 4 + lg) ^ (row & 7);
        bg[j] = *(const short8*)(&Bs[s][0] + row * 64 + rg * 8);
      }
      asm volatile("s_waitcnt lgkmcnt(0)" ::: "memory");
      __builtin_amdgcn_sched_barrier(0);
      __builtin_amdgcn_s_setprio(1);
      #pragma unroll
      for (int i = 0; i < 8; ++i)
        #pragma unroll
        for (int j = 0; j < 4; ++j)
          acc[i][j] = __builtin_amdgcn_mfma_f32_16x16x32_bf16(af[i], bg[j], acc[i][j], 0, 0, 0);
      __builtin_amdgcn_s_setprio(0);
    }
    __builtin_amdgcn_s_barrier();                   // all reads of slot s done
  }

  // epilogue; C layout: col = lane&15, row = (lane>>4)*4 + reg
  #pragma unroll
  for (int i = 0; i < 8; ++i)
    #pragma unroll
    for (int r = 0; r < 4; ++r) {
      const int m = m0 + wm * 128 + i * 16 + lg * 4 + r;
      #pragma unroll
      for (int j = 0; j < 4; ++j) {
        const int n = n0 + wn * 64 + j * 16 + lr;
        C[(size_t)m * NST + n] = f2bf(acc[i][j][r]);
      }
    }
}

// ---------------------------------------------------------------------------
// Alpha-combine + fused epilogues. y[t,d] = sum_k alpha[t,k]*Z[t,k*2048+d].
// mode 0: bf16 out = y                      (gate)
// mode 1: fp32 out = x + y                  (o residual -> x_attn)
// mode 2: bf16 out = silu(gate)*y           (up; gate read bf16, in-place ok)
// mode 3: fp32 out = x + (xattn + y - x)*is (down final)
// One block per token; thread handles 8 consecutive d.
__global__ __launch_bounds__(256)
void combine_kernel(const short* __restrict__ Z,      // (4096, 8192) bf16
                    const float* __restrict__ alpha,  // (4096, 4)
                    const int mode,
                    const float* __restrict__ x,
                    const float* __restrict__ xattn,
                    const float* __restrict__ iter_s,
                    const short* __restrict__ gate,
                    void* __restrict__ outp)
{
  const int t = blockIdx.x;
  const int d0 = threadIdx.x * 8;
  const float a0 = alpha[(size_t)t*4],   a1 = alpha[(size_t)t*4+1],
              a2 = alpha[(size_t)t*4+2], a3 = alpha[(size_t)t*4+3];
  const short* zr = Z + (size_t)t * 8192 + d0;
  short8 z0 = *(const short8*)(zr);
  short8 z1 = *(const short8*)(zr + 2048);
  short8 z2 = *(const short8*)(zr + 4096);
  short8 z3 = *(const short8*)(zr + 6144);
  float y[8];
  #pragma unroll
  for (int j = 0; j < 8; ++j)
    y[j] = a0*bf2f(z0[j]) + a1*bf2f(z1[j]) + a2*bf2f(z2[j]) + a3*bf2f(z3[j]);
  const size_t base = (size_t)t * DD + d0;
  if (mode == 0) {
    short8 o;
    #pragma unroll
    for (int j = 0; j < 8; ++j) o[j] = f2bf(y[j]);
    *(short8*)((short*)outp + base) = o;
  } else if (mode == 1) {
    float4 x0 = *(const float4*)(x + base);
    float4 x1 = *(const float4*)(x + base + 4);
    float xv[8] = {x0.x,x0.y,x0.z,x0.w,x1.x,x1.y,x1.z,x1.w};
    float* op = (float*)outp;
    #pragma unroll
    for (int j = 0; j < 8; ++j) op[base + j] = xv[j] + y[j];
  } else if (mode == 2) {
    short8 gv = *(const short8*)(gate + base);
    short8 o;
    #pragma unroll
    for (int j = 0; j < 8; ++j) {
      float xg = bf2f(gv[j]);
      float s = xg / (1.0f + __expf(-xg));
      o[j] = f2bf(s * y[j]);
    }
    *(short8*)((short*)outp + base) = o;
  } else {
    const float is = *iter_s;
    float4 x0 = *(const float4*)(x + base);
    float4 x1 = *(const float4*)(x + base + 4);
    float4 t0 = *(const float4*)(xattn + base);
    float4 t1 = *(const float4*)(xattn + base + 4);
    float xv[8] = {x0.x,x0.y,x0.z,x0.w,x1.x,x1.y,x1.z,x1.w};
    float tv[8] = {t0.x,t0.y,t0.z,t0.w,t1.x,t1.y,t1.z,t1.w};
    float* op = (float*)outp;
    #pragma unroll
    for (int j = 0; j < 8; ++j) op[base + j] = xv[j] + (tv[j] + y[j] - xv[j]) * is;
  }
}

// ---------------------------------------------------------------------------
// Transpose V out of qkv into (B*H, HD, T) bf16 so attention can stage V^T
// with vector loads.
__global__ __launch_bounds__(256)
void transpose_v_kernel(const short* __restrict__ qkv, short* __restrict__ vt)
{
  __shared__ __align__(16) short tile[64][72];
  const int t0 = blockIdx.x * 64;
  const int hd0 = blockIdx.y * 64;
  const int bh = blockIdx.z;
  const int b = bh >> 4, h = bh & 15;
  const int tid = threadIdx.x;
  #pragma unroll
  for (int c = 0; c < 2; ++c) {
    int ci = tid + 256 * c;
    int tr = ci >> 3, c8 = ci & 7;
    *(short8*)&tile[tr][c8*8] =
      *(const short8*)(qkv + (size_t)(b*2048 + t0 + tr)*6144 + 4096 + h*HD_ + hd0 + c8*8);
  }
  __syncthreads();
  #pragma unroll
  for (int c = 0; c < 2; ++c) {
    int ci = tid + 256 * c;
    int hr = ci >> 3, c8 = ci & 7;
    short8 o;
    #pragma unroll
    for (int j = 0; j < 8; ++j) o[j] = tile[c8*8 + j][hr];
    *(short8*)(vt + (size_t)(bh*HD_ + hd0 + hr)*2048 + t0 + c8*8) = o;
  }
}

// ---------------------------------------------------------------------------
// Flash attention (causal). Block = 4 waves; wave w owns 16 q-rows.
// Tiles of 32 keys; QK^T and PV via 16x16x32 bf16 MFMA; P goes through LDS
// (C-layout -> A-layout).
__global__ __launch_bounds__(256, 2)
void attn_kernel(const short* __restrict__ qkv,   // (4096, 6144) bf16
                 const short* __restrict__ vt,    // (32, 128, 2048) bf16
                 short* __restrict__ attnout)     // (4096, 2048) bf16
{
  __shared__ __align__(16) short Ks[32][136];
  __shared__ __align__(16) short Vt[128][40];
  __shared__ __align__(16) short Ps[4][16][40];
  const int bid = blockIdx.x;
  const int qt = bid & 31, bh = bid >> 5;
  const int b = bh >> 4, h = bh & 15;
  const int q0 = qt * 64;
  const int tid = threadIdx.x, lane = tid & 63, w = tid >> 6;
  const int lr = lane & 15, lg = lane >> 4;
  const int q0w = q0 + w * 16;

  // preload Q fragments: A[m=lr][k = s*32 + lg*8 + j]
  short8 qf[4];
  {
    const size_t qbase = (size_t)(b*2048 + q0w + lr) * 6144 + h * HD_;
    #pragma unroll
    for (int s = 0; s < 4; ++s)
      qf[s] = *(const short8*)(qkv + qbase + s*32 + lg*8);
  }
  float m_run[4], l_run[4];
  f32x4 acc[8];
  #pragma unroll
  for (int r = 0; r < 4; ++r) { m_run[r] = -1e30f; l_run[r] = 0.f; }
  #pragma unroll
  for (int dt = 0; dt < 8; ++dt) acc[dt] = zero4();

  const int ntiles = (q0 + 64) >> 5;
  for (int jt = 0; jt < ntiles; ++jt) {
    const int j0 = jt << 5;
    // stage K tile (32 x 128) and V^T tile (128 x 32)
    #pragma unroll
    for (int c = 0; c < 2; ++c) {
      int ci = tid + 256 * c;
      int key = ci >> 4, hd8 = ci & 15;
      *(short8*)&Ks[key][hd8*8] =
        *(const short8*)(qkv + (size_t)(b*2048 + j0 + key)*6144 + 2048 + h*HD_ + hd8*8);
    }
    #pragma unroll
    for (int c = 0; c < 2; ++c) {
      int ci = tid + 256 * c;
      int hd = ci >> 2, k8 = ci & 3;
      *(short8*)&Vt[hd][k8*8] =
        *(const short8*)(vt + (size_t)(bh*HD_ + hd)*2048 + j0 + k8*8);
    }
    __syncthreads();
    // S = Q K^T  (two 16-key halves)
    f32x4 sc0 = zero4(), sc1 = zero4();
    #pragma unroll
    for (int s = 0; s < 4; ++s) {
      short8 kb0 = *(const short8*)&Ks[lr][s*32 + lg*8];
      short8 kb1 = *(const short8*)&Ks[16 + lr][s*32 + lg*8];
      sc0 = __builtin_amdgcn_mfma_f32_16x16x32_bf16(qf[s], kb0, sc0, 0, 0, 0);
      sc1 = __builtin_amdgcn_mfma_f32_16x16x32_bf16(qf[s], kb1, sc1, 0, 0, 0);
    }
    // online softmax (per row r; columns spread over lr lanes)
    float pv0[4], pv1[4], al[4];
    #pragma unroll
    for (int r = 0; r < 4; ++r) {
      const int q = q0w + lg*4 + r;
      float v0 = sc0[r] * ASCALE; if (j0 + lr > q)      v0 = -1e30f;
      float v1 = sc1[r] * ASCALE; if (j0 + 16 + lr > q) v1 = -1e30f;
      float mx = fmaxf(v0, v1);
      mx = fmaxf(mx, __shfl_xor(mx, 1, 16));
      mx = fmaxf(mx, __shfl_xor(mx, 2, 16));
      mx = fmaxf(mx, __shfl_xor(mx, 4, 16));
      mx = fmaxf(mx, __shfl_xor(mx, 8, 16));
      const float mnew = fmaxf(m_run[r], mx);
      const float a = __expf(m_run[r] - mnew);
      v0 = __expf(v0 - mnew);
      v1 = __expf(v1 - mnew);
      float rs = v0 + v1;
      rs += __shfl_xor(rs, 1, 16);
      rs += __shfl_xor(rs, 2, 16);
      rs += __shfl_xor(rs, 4, 16);
      rs += __shfl_xor(rs, 8, 16);
      l_run[r] = l_run[r] * a + rs;
      m_run[r] = mnew;
      al[r] = a; pv0[r] = v0; pv1[r] = v1;
    }
    #pragma unroll
    for (int dt = 0; dt < 8; ++dt)
      #pragma unroll
      for (int r = 0; r < 4; ++r) acc[dt][r] *= al[r];
    // P: C-layout -> LDS -> A-layout
    #pragma unroll
    for (int r = 0; r < 4; ++r) {
      Ps[w][lg*4 + r][lr]      = f2bf(pv0[r]);
      Ps[w][lg*4 + r][16 + lr] = f2bf(pv1[r]);
    }
    short8 pa = *(const short8*)&Ps[w][lr][lg*8];
    #pragma unroll
    for (int dt = 0; dt < 8; ++dt) {
      short8 vb = *(const short8*)&Vt[dt*16 + lr][lg*8];
      acc[dt] = __builtin_amdgcn_mfma_f32_16x16x32_bf16(pa, vb, acc[dt], 0, 0, 0);
    }
    __syncthreads();
  }
  #pragma unroll
  for (int dt = 0; dt < 8; ++dt) {
    #pragma unroll
    for (int r = 0; r < 4; ++r) {
      const int q = q0w + lg*4 + r;
      attnout[(size_t)(b*2048 + q)*2048 + h*HD_ + dt*16 + lr] = f2bf(acc[dt][r] / l_run[r]);
    }
  }
}

// ---------------------------------------------------------------------------
extern "C" void kernel_launch(void* const* d_in, const int* in_sizes, int n_in,
                              void* d_out, int out_size, void* d_ws, size_t ws_size,
                              hipStream_t stream) {
  const float* x          = (const float*)d_in[0];
  const float* gamma      = (const float*)d_in[1];
  const float* beta       = (const float*)d_in[2];
  const float* iter_scale = (const float*)d_in[3];
  const float* qkv_bases  = (const float*)d_in[4];
  const float* o_bases    = (const float*)d_in[5];
  const float* gate_bases = (const float*)d_in[6];
  const float* up_bases   = (const float*)d_in[7];
  const float* down_bases = (const float*)d_in[8];
  const float* route_qkv  = (const float*)d_in[9];
  const float* route_o    = (const float*)d_in[10];
  const float* route_gate = (const float*)d_in[11];
  const float* route_up   = (const float*)d_in[12];
  const float* route_down = (const float*)d_in[13];
  const float* bias_qkv   = (const float*)d_in[14];
  const float* bias_o     = (const float*)d_in[15];
  const float* bias_gate  = (const float*)d_in[16];
  const float* bias_up    = (const float*)d_in[17];
  const float* bias_down  = (const float*)d_in[18];
  const float* norm1_w    = (const float*)d_in[19];
  const float* norm2_w    = (const float*)d_in[20];
  const int*   li         = (const int*)d_in[21];

  float* out0 = (float*)d_out;                  // (B,T,D) fp32
  float* aout = out0 + (size_t)BT * DD;         // a_qkv (B,T,4) fp32

  char* ws = (char*)d_ws;
  short* hbuf    = (short*)(ws + 0);            // 16.78 MB  (h / h2, bf16)
  float* alpha   = (float*)(ws + 16777216);     // 64 KB
  short* Zbuf    = (short*)(ws + 16842752);     // 67.1 MB  (Z wide / Aexp qkv)
  short* Bconv   = (short*)(ws + 83951616);     // 100.7 MB (bf16 bases, reused)
  short* qkvbuf  = (short*)(ws + 184614912);    // 50.3 MB  (BT x 6144 bf16)
  short* vtbuf   = (short*)(ws + 234946560);    // 16.78 MB
  short* attnout = (short*)(ws + 251723776);    // 16.78 MB ; total 268.5 MB
  // aliases (lifetimes are disjoint): after attn, qkvbuf region splits into
  // x_attn (fp32, 33.55 MB) + gate/ffn (bf16, 16.78 MB).
  float* x_attn  = (float*)(ws + 184614912);
  short* gatebuf = (short*)(ws + 218169344);    // also ffn_in (in-place mode 2)

  const int NCH_QKV = 50331648 / 8;   // qkv_bases chunks
  const int NCH_D   = 16777216 / 8;   // o/gate/up/down bases chunks

  // h = rmsnorm(x, norm1_w)*gamma + beta
  rmsnorm_kernel<<<BT, 256, 0, stream>>>(x, norm1_w, gamma, beta, hbuf);
  // qkv mixed linear (expand form, emits a_qkv)
  cvt_bf16_kernel<<<NCH_QKV/256, 256, 0, stream>>>(qkv_bases, Bconv, NCH_QKV);
  route_kernel<<<BT, 64, 0, stream>>>(hbuf, route_qkv, bias_qkv, li, alpha, aout);
  expand_kernel<<<BT, 256, 0, stream>>>(hbuf, alpha, Zbuf);
  gemm_dp<true, 8192, 8192, 6144><<<dim3(24, 16), 512, 0, stream>>>(Zbuf, Bconv, qkvbuf);
  // attention
  transpose_v_kernel<<<dim3(32, 2, 32), 256, 0, stream>>>(qkvbuf, vtbuf);
  attn_kernel<<<1024, 256, 0, stream>>>(qkvbuf, vtbuf, attnout);
  // o mixed linear (wide form) + residual -> x_attn (fp32)
  cvt_bf16_kernel<<<NCH_D/256, 256, 0, stream>>>(o_bases, Bconv, NCH_D);
  route_kernel<<<BT, 64, 0, stream>>>(attnout, route_o, bias_o, li, alpha, nullptr);
  gemm_dp<false, 2048, 2048, 8192><<<dim3(32, 16), 512, 0, stream>>>(attnout, Bconv, Zbuf);
  combine_kernel<<<BT, 256, 0, stream>>>(Zbuf, alpha, 1, x, nullptr, nullptr,
                                         nullptr, x_attn);
  // h2 = rmsnorm(x_attn, norm2_w)*gamma + beta
  rmsnorm_kernel<<<BT, 256, 0, stream>>>(x_attn, norm2_w, gamma, beta, hbuf);
  // gate (wide form)
  cvt_bf16_kernel<<<NCH_D/256, 256, 0, stream>>>(gate_bases, Bconv, NCH_D);
  route_kernel<<<BT, 64, 0, stream>>>(hbuf, route_gate, bias_gate, li, alpha, nullptr);
  gemm_dp<false, 2048, 2048, 8192><<<dim3(32, 16), 512, 0, stream>>>(hbuf, Bconv, Zbuf);
  combine_kernel<<<BT, 256, 0, stream>>>(Zbuf, alpha, 0, nullptr, nullptr, nullptr,
                                         nullptr, gatebuf);
  // up (wide form) + fused silu(gate)*up -> ffn_in (in-place over gatebuf)
  cvt_bf16_kernel<<<NCH_D/256, 256, 0, stream>>>(up_bases, Bconv, NCH_D);
  route_kernel<<<BT, 64, 0, stream>>>(hbuf, route_up, bias_up, li, alpha, nullptr);
  gemm_dp<false, 2048, 2048, 8192><<<dim3(32, 16), 512, 0, stream>>>(hbuf, Bconv, Zbuf);
  combine_kernel<<<BT, 256, 0, stream>>>(Zbuf, alpha, 2, nullptr, nullptr, nullptr,
                                         gatebuf, gatebuf);
  // down (wide form) + final residual/iter_scale -> out0
  cvt_bf16_kernel<<<NCH_D/256, 256, 0, stream>>>(down_bases, Bconv, NCH_D);
  route_kernel<<<BT, 64, 0, stream>>>(gatebuf, route_down, bias_down, li, alpha, nullptr);
  gemm_dp<false, 2048, 2048, 8192><<<dim3(32, 16), 512, 0, stream>>>(gatebuf, Bconv, Zbuf);
  combine_kernel<<<BT, 256, 0, stream>>>(Zbuf, alpha, 3, x, x_attn, iter_scale,
                                         nullptr, out0);
}